// Round 3
// baseline (182.414 us; speedup 1.0000x reference)
//
#include <hip/hip_runtime.h>
#include <cfloat>
#include <math.h>

#define B_ 4
#define L_ 1024
#define D_ 8
#define OUT_ 224
#define NPIX (B_ * 2 * D_ * OUT_ * OUT_)   // 3211264
#define NT4  (NPIX / 4)                    // 802816 = 3136 * 256 exactly
#define PI_F 3.14159265358979323846f
#define TBL 128                            // float offset of per-(b,d) tables in ws
#define TSTR 896                           // per-(b,d): CL[224] SL[224] RV0[224] RV1[224]

__device__ __forceinline__ float clipnorm(float v, float lo, float inv2, int degen) {
    float xn = degen ? -1.0f : ((v - lo) * inv2 - 1.0f);
    return fminf(fmaxf(xn, -1.0f + 1e-6f), 1.0f - 1e-6f);
}
__device__ __forceinline__ unsigned fkey(float f) {
    unsigned u = __float_as_uint(f);
    return (u & 0x80000000u) ? ~u : (u | 0x80000000u);
}
__device__ __forceinline__ float unfkey(unsigned k) {
    unsigned u = (k & 0x80000000u) ? (k ^ 0x80000000u) : ~k;
    return __uint_as_float(u);
}

// One block per (b,d). 1024 threads.
__global__ __launch_bounds__(1024) void k_stats(const float* __restrict__ x,
                                                float* __restrict__ ws) {
    __shared__ float t[L_];
    __shared__ float csort[L_], ssort[L_], w[L_];
    __shared__ unsigned cbuf[2][8];
    __shared__ unsigned umin_a, umax_a, umin_b, umax_b, succ_bits;

    const int tid  = threadIdx.x;
    const int lane = tid & 63;
    const int blk  = blockIdx.x;
    const int b = blk >> 3, d = blk & 7;

    if (tid == 0) {
        umin_a = 0xFFFFFFFFu; umax_a = 0u;
        umin_b = 0xFFFFFFFFu; umax_b = 0u;
        succ_bits = 0xFFFFFFFFu;
    }
    if (tid < 16) ((unsigned*)cbuf)[tid] = 0u;
    __syncthreads();

    // ---- global min/max over all of x ----
    {
        const float4* x4 = (const float4*)x;
        float lo = FLT_MAX, hi = -FLT_MAX;
        for (int i = tid; i < (B_ * L_ * D_) / 4; i += 1024) {
            float4 q = x4[i];
            lo = fminf(fminf(fminf(lo, q.x), q.y), fminf(q.z, q.w));
            hi = fmaxf(fmaxf(fmaxf(hi, q.x), q.y), fmaxf(q.z, q.w));
        }
#pragma unroll
        for (int off = 32; off; off >>= 1) {
            lo = fminf(lo, __shfl_down(lo, off));
            hi = fmaxf(hi, __shfl_down(hi, off));
        }
        if (lane == 0) { atomicMin(&umin_a, fkey(lo)); atomicMax(&umax_a, fkey(hi)); }
    }
    __syncthreads();
    const float glo = unfkey(umin_a), ghi = unfkey(umax_a);
    if (blk == 0 && tid == 0) { ws[0] = glo; ws[1] = ghi; }
    const float rng  = ghi - glo;
    const int degen  = rng < 1e-8f;
    const float inv2 = 2.0f / (rng + 1e-8f);

    // ---- per-(b,d) axis tables for k_out (separable bilinear) ----
    if (tid < 2 * OUT_) {
        const float scale = (float)L_ / (float)OUT_;
        int o = tid & 255; if (tid >= OUT_) o = tid - OUT_;
        float fx = (o + 0.5f) * scale - 0.5f;
        int x0 = (int)fx; float wx = fx - (float)x0;
        float q0 = x[(b * L_ + x0) * D_ + d];
        float q1 = x[(b * L_ + x0 + 1) * D_ + d];
        float* base = ws + TBL + blk * TSTR;
        if (tid < OUT_) {
            float c0 = clipnorm(q0, glo, inv2, degen), c1 = clipnorm(q1, glo, inv2, degen);
            float s0 = sqrtf(fmaxf(0.0f, 1.0f - c0 * c0)), s1 = sqrtf(fmaxf(0.0f, 1.0f - c1 * c1));
            base[o]        = c0 + wx * (c1 - c0);   // CL
            base[OUT_ + o] = s0 + wx * (s1 - s0);   // SL
        } else {
            base[448 + o] = q0;                     // RV0
            base[672 + o] = q1;                     // RV1
        }
    }

    // ---- bitonic sort of this (b,d) series; register + shfl, LDS only j>=64 ----
    float v = x[(b * L_ + tid) * D_ + d];
    for (int k = 2; k <= L_; k <<= 1) {
        bool up = ((tid & k) == 0);
        for (int j = k >> 1; j > 0; j >>= 1) {
            bool lower = ((tid & j) == 0);
            float other;
            if (j >= 64) {
                __syncthreads();
                t[tid] = v;
                __syncthreads();
                other = t[tid ^ j];
            } else {
                other = __shfl_xor(v, j);
            }
            float mn = fminf(v, other), mx = fmaxf(v, other);
            v = (lower == up) ? mn : mx;
        }
    }
    __syncthreads();
    t[tid] = v;

    {
        float c = clipnorm(v, glo, inv2, degen);
        csort[tid] = c;
        ssort[tid] = sqrtf(fmaxf(0.0f, 1.0f - c * c));
        w[tid]     = acosf(c);
    }
    __syncthreads();

    // ---- GAF min/max ----
    {
        float wi = w[tid];
        int jstar = -1;
        if (wi + w[0] >= PI_F) {
            int a = 0, bh = L_ - 1;
            while (a < bh) { int m = (a + bh + 1) >> 1; if (wi + w[m] >= PI_F) a = m; else bh = m - 1; }
            jstar = a;
        }
        float ci = csort[tid], si = ssort[tid];
        float mn = FLT_MAX, mx = -FLT_MAX;
        int cands[4] = {0, L_ - 1, jstar, jstar + 1};
#pragma unroll
        for (int q = 0; q < 4; q++) {
            int j = cands[q];
            if (j >= 0 && j < L_) {
                float g = ci * csort[j] - si * ssort[j];
                mn = fminf(mn, g); mx = fmaxf(mx, g);
            }
        }
#pragma unroll
        for (int off = 32; off; off >>= 1) {
            mn = fminf(mn, __shfl_down(mn, off));
            mx = fmaxf(mx, __shfl_down(mx, off));
        }
        if (lane == 0) { atomicMin(&umin_b, fkey(mn)); atomicMax(&umax_b, fkey(mx)); }
        __syncthreads();
        if (tid == 0) {
            ws[2 + blk * 3 + 0] = unfkey(umin_b);
            ws[2 + blk * 3 + 1] = unfkey(umax_b);
        }
    }

    // ---- RP quantile via 8-ary windowed bit-bisection ----
    const float ti = v;
    int pass = 0;

    // windows at v=0
    int jlo0; { int a2 = 0, b2 = tid;
        while (a2 < b2) { int m2 = (a2 + b2) >> 1; if (ti - t[m2] <= 0.0f) b2 = m2; else a2 = m2 + 1; }
        jlo0 = a2; }
    int jhi0; { int a2 = tid, b2 = L_ - 1;
        while (a2 < b2) { int m2 = (a2 + b2 + 1) >> 1; if (t[m2] - ti <= 0.0f) a2 = m2; else b2 = m2 - 1; }
        jhi0 = a2; }

    unsigned tot0;
    {
        unsigned c0 = (unsigned)(jhi0 - jlo0 + 1);
#pragma unroll
        for (int off = 32; off; off >>= 1) c0 += __shfl_down(c0, off);
        if (lane == 0) atomicAdd(&cbuf[0][1], c0);
        __syncthreads();
        tot0 = cbuf[0][1];
        if (tid < 8) cbuf[1][tid] = 0u;
        __syncthreads();
        pass = 1;
    }

    const unsigned k1 = 104858u, k2 = 104859u;  // ranks around 0.1*(L^2-1)=104857.5
    const float dmax = t[L_ - 1] - t[0];

    float v1; unsigned cntV1; int jloV1, jhiV1;
    if (tot0 >= k1) {
        v1 = 0.0f; cntV1 = tot0; jloV1 = jlo0; jhiV1 = jhi0;
    } else {
        unsigned vlo = 0u, vhi = __float_as_uint(dmax);
        unsigned cntHi = (unsigned)(L_ * L_);
        int jloLo = jlo0, jhiLo = jhi0;   // windows at vlo
        int jloHi = 0,    jhiHi = L_ - 1; // windows at vhi
        unsigned cntLo = tot0; (void)cntLo;

        while (vhi - vlo > 1u) {
            unsigned width = vhi - vlo;
            int ne = (width - 1u < 7u) ? (int)(width - 1u) : 7;
            unsigned vb[8]; float vf[8];
#pragma unroll
            for (int e = 1; e <= 7; e++) {
                unsigned off = (unsigned)(((unsigned long long)width * (unsigned)e) / (unsigned)(ne + 1));
                vb[e] = vlo + off;
                vf[e] = __uint_as_float(vb[e]);
            }
            int aL[8], bL[8], aH[8], bH[8];
#pragma unroll
            for (int e = 1; e <= 7; e++) { aL[e] = jloHi; bL[e] = jloLo; aH[e] = jhiLo; bH[e] = jhiHi; }
            bool any = true;
            while (any) {
                any = false;
                float tvL[8], tvH[8];
                bool acL[8], acH[8];
#pragma unroll
                for (int e = 1; e <= 7; e++) {
                    acL[e] = (e <= ne) && (aL[e] < bL[e]);
                    if (acL[e]) tvL[e] = t[(aL[e] + bL[e]) >> 1];
                    acH[e] = (e <= ne) && (aH[e] < bH[e]);
                    if (acH[e]) tvH[e] = t[(aH[e] + bH[e] + 1) >> 1];
                }
#pragma unroll
                for (int e = 1; e <= 7; e++) {
                    if (acL[e]) {
                        int m = (aL[e] + bL[e]) >> 1;
                        if (ti - tvL[e] <= vf[e]) bL[e] = m; else aL[e] = m + 1;
                        any = true;
                    }
                    if (acH[e]) {
                        int m = (aH[e] + bH[e] + 1) >> 1;
                        if (tvH[e] - ti <= vf[e]) aH[e] = m; else bH[e] = m - 1;
                        any = true;
                    }
                }
            }
            // counts + block reduce
            int pb = pass & 1;
#pragma unroll
            for (int e = 1; e <= 7; e++) {
                if (e <= ne) {
                    unsigned c = (unsigned)(aH[e] - aL[e] + 1);
#pragma unroll
                    for (int off = 32; off; off >>= 1) c += __shfl_down(c, off);
                    if (lane == 0) atomicAdd(&cbuf[pb][e], c);
                }
            }
            __syncthreads();
            unsigned tot[8];
#pragma unroll
            for (int e = 1; e <= 7; e++) tot[e] = cbuf[pb][e];
            if (tid < 8) cbuf[(pass + 1) & 1][tid] = 0u;
            __syncthreads();
            pass++;

            int estar = 0;
#pragma unroll
            for (int e = 7; e >= 1; e--) if (e <= ne && tot[e] >= k1) estar = e;

            if (estar == 0) {
#pragma unroll
                for (int e = 1; e <= 7; e++) if (e == ne) {
                    vlo = vb[e]; jloLo = aL[e]; jhiLo = aH[e];
                }
            } else {
#pragma unroll
                for (int e = 1; e <= 7; e++) if (e == estar) {
                    vhi = vb[e]; cntHi = tot[e]; jloHi = aL[e]; jhiHi = aH[e];
                }
                if (estar > 1) {
#pragma unroll
                    for (int e = 1; e <= 7; e++) if (e == estar - 1) {
                        vlo = vb[e]; jloLo = aL[e]; jhiLo = aH[e];
                    }
                }
            }
        }
        v1 = __uint_as_float(vhi); cntV1 = cntHi; jloV1 = jloHi; jhiV1 = jhiHi;
    }

    float thr;
    if (cntV1 >= k2) {
        thr = v1;
    } else {
        float s = FLT_MAX;
        if (jloV1 > 0)      s = fminf(s, ti - t[jloV1 - 1]);
        if (jhiV1 < L_ - 1) s = fminf(s, t[jhiV1 + 1] - ti);
#pragma unroll
        for (int off = 32; off; off >>= 1) s = fminf(s, __shfl_down(s, off));
        if (lane == 0) atomicMin(&succ_bits, __float_as_uint(s));
        __syncthreads();
        float v2 = __uint_as_float(succ_bits);
        thr = v1 + (v2 - v1) * 0.5f;
    }
    if (tid == 0) ws[2 + blk * 3 + 2] = thr;
}

// One thread per 4 consecutive pixels; per-plane axis tables staged in LDS.
__global__ __launch_bounds__(256) void k_out(const float* __restrict__ ws,
                                             float4* __restrict__ out4) {
    __shared__ float lds[448];
    __shared__ float sc[3];

    const int tid = threadIdx.x;
    // block covers 1024 pixels; plane = 50176 = 49 blocks exactly -> (b,c) uniform
    int plane = blockIdx.x / 49;
    int c = plane & 15, b = plane >> 4, d = c & 7;

    const float* tb = ws + TBL + (b * 8 + d) * TSTR + ((c < 8) ? 0 : 448);
    for (int i = tid; i < 448; i += 256) lds[i] = tb[i];
    if (tid == 0) {
        if (c < 8) {
            float mn = ws[2 + (b * 8 + d) * 3 + 0];
            float mx = ws[2 + (b * 8 + d) * 3 + 1];
            float g = mx - mn;
            sc[0] = mn;
            sc[1] = (g < 1e-8f) ? 0.0f : 1.0f / (g + 1e-8f);
            sc[2] = (g < 1e-8f) ? 1.0f : 0.0f;
        } else {
            sc[0] = ws[2 + (b * 8 + d) * 3 + 2];
        }
    }
    __syncthreads();

    int tix = blockIdx.x * 256 + tid;
    int pix0 = tix << 2;
    int ox0 = pix0 % OUT_;
    int oy  = (pix0 / OUT_) % OUT_;

    float res[4];
    if (c < 8) {
        float mn = sc[0], ginv = sc[1];
        bool gdeg = sc[2] != 0.0f;
        float Cr = lds[oy], Sr = lds[OUT_ + oy];
#pragma unroll
        for (int p = 0; p < 4; p++) {
            float g = Cr * lds[ox0 + p] - Sr * lds[OUT_ + ox0 + p];
            res[p] = gdeg ? 0.0f : (g - mn) * ginv;
        }
    } else {
        float thr = sc[0];
        const float scale = (float)L_ / (float)OUT_;
        float fy = (oy + 0.5f) * scale - 0.5f;
        int y0 = (int)fy; float wy = fy - (float)y0;
        float r0 = lds[oy], r1 = lds[OUT_ + oy];
#pragma unroll
        for (int p = 0; p < 4; p++) {
            float fx = (ox0 + p + 0.5f) * scale - 0.5f;
            int x0 = (int)fx; float wx = fx - (float)x0;
            float q0 = lds[ox0 + p], q1 = lds[OUT_ + ox0 + p];
            float v00 = (fabsf(r0 - q0) <= thr) ? 1.0f : 0.0f;
            float v01 = (fabsf(r0 - q1) <= thr) ? 1.0f : 0.0f;
            float v10 = (fabsf(r1 - q0) <= thr) ? 1.0f : 0.0f;
            float v11 = (fabsf(r1 - q1) <= thr) ? 1.0f : 0.0f;
            float top = v00 + wx * (v01 - v00);
            float bot = v10 + wx * (v11 - v10);
            res[p] = top + wy * (bot - top);
        }
    }
    out4[tix] = make_float4(res[0], res[1], res[2], res[3]);
}

extern "C" void kernel_launch(void* const* d_in, const int* in_sizes, int n_in,
                              void* d_out, int out_size, void* d_ws, size_t ws_size,
                              hipStream_t stream) {
    const float* x = (const float*)d_in[0];
    float* ws = (float*)d_ws;

    k_stats<<<B_ * D_, 1024, 0, stream>>>(x, ws);
    k_out<<<NT4 / 256, 256, 0, stream>>>(ws, (float4*)d_out);
}

// Round 4
// 133.862 us; speedup vs baseline: 1.3627x; 1.3627x over previous
//
#include <hip/hip_runtime.h>
#include <cfloat>
#include <math.h>

#define B_ 4
#define L_ 1024
#define D_ 8
#define OUT_ 224
#define NPIX (B_ * 2 * D_ * OUT_ * OUT_)   // 3211264
#define NT4  (NPIX / 4)                    // 802816 = 3136 * 256 exactly
#define PI_F 3.14159265358979323846f
#define TBL 128                            // float offset of per-(b,d) tables in ws
#define TSTR 896                           // per-(b,d): CL[224] SL[224] RV0[224] RV1[224]

__device__ __forceinline__ float clipnorm(float v, float lo, float inv2, int degen) {
    float xn = degen ? -1.0f : ((v - lo) * inv2 - 1.0f);
    return fminf(fmaxf(xn, -1.0f + 1e-6f), 1.0f - 1e-6f);
}
__device__ __forceinline__ unsigned fkey(float f) {
    unsigned u = __float_as_uint(f);
    return (u & 0x80000000u) ? ~u : (u | 0x80000000u);
}
__device__ __forceinline__ float unfkey(unsigned k) {
    unsigned u = (k & 0x80000000u) ? (k ^ 0x80000000u) : ~k;
    return __uint_as_float(u);
}

// One block per (b,d). 1024 threads.
__global__ __launch_bounds__(1024) void k_stats(const float* __restrict__ x,
                                                float* __restrict__ ws) {
    __shared__ float t[L_];
    __shared__ float csort[L_], ssort[L_], w[L_];
    __shared__ unsigned cbuf[2];
    __shared__ unsigned umin_a, umax_a, umin_b, umax_b, succ_bits;
    __shared__ unsigned cand_n;
    __shared__ float cand[64];
    __shared__ float bc_v1v2[2];

    const int tid  = threadIdx.x;
    const int lane = tid & 63;
    const int blk  = blockIdx.x;
    const int b = blk >> 3, d = blk & 7;

    if (tid == 0) {
        umin_a = 0xFFFFFFFFu; umax_a = 0u;
        umin_b = 0xFFFFFFFFu; umax_b = 0u;
        succ_bits = 0xFFFFFFFFu;
        cand_n = 0u;
        cbuf[0] = 0u; cbuf[1] = 0u;
    }
    __syncthreads();

    // ---- global min/max over all of x (x = 128KB, L2-hot) ----
    {
        const float4* x4 = (const float4*)x;
        float lo = FLT_MAX, hi = -FLT_MAX;
        for (int i = tid; i < (B_ * L_ * D_) / 4; i += 1024) {
            float4 q = x4[i];
            lo = fminf(fminf(fminf(lo, q.x), q.y), fminf(q.z, q.w));
            hi = fmaxf(fmaxf(fmaxf(hi, q.x), q.y), fmaxf(q.z, q.w));
        }
#pragma unroll
        for (int off = 32; off; off >>= 1) {
            lo = fminf(lo, __shfl_down(lo, off));
            hi = fmaxf(hi, __shfl_down(hi, off));
        }
        if (lane == 0) { atomicMin(&umin_a, fkey(lo)); atomicMax(&umax_a, fkey(hi)); }
    }
    __syncthreads();
    const float glo = unfkey(umin_a), ghi = unfkey(umax_a);
    if (blk == 0 && tid == 0) { ws[0] = glo; ws[1] = ghi; }
    const float rng  = ghi - glo;
    const int degen  = rng < 1e-8f;
    const float inv2 = 2.0f / (rng + 1e-8f);

    // ---- per-(b,d) axis tables for k_out (separable bilinear) ----
    if (tid < 2 * OUT_) {
        const float scale = (float)L_ / (float)OUT_;
        int o = (tid < OUT_) ? tid : tid - OUT_;
        float fx = (o + 0.5f) * scale - 0.5f;
        int x0 = (int)fx; float wx = fx - (float)x0;
        float q0 = x[(b * L_ + x0) * D_ + d];
        float q1 = x[(b * L_ + x0 + 1) * D_ + d];
        float* base = ws + TBL + blk * TSTR;
        if (tid < OUT_) {
            float c0 = clipnorm(q0, glo, inv2, degen), c1 = clipnorm(q1, glo, inv2, degen);
            float s0 = sqrtf(fmaxf(0.0f, 1.0f - c0 * c0)), s1 = sqrtf(fmaxf(0.0f, 1.0f - c1 * c1));
            base[o]        = c0 + wx * (c1 - c0);   // CL
            base[OUT_ + o] = s0 + wx * (s1 - s0);   // SL
        } else {
            base[448 + o] = q0;                     // RV0
            base[672 + o] = q1;                     // RV1
        }
    }

    // ---- bitonic sort of this (b,d) series; register + shfl, LDS only j>=64 ----
    float v = x[(b * L_ + tid) * D_ + d];
    for (int k = 2; k <= L_; k <<= 1) {
        bool up = ((tid & k) == 0);
        for (int j = k >> 1; j > 0; j >>= 1) {
            bool lower = ((tid & j) == 0);
            float other;
            if (j >= 64) {
                __syncthreads();
                t[tid] = v;
                __syncthreads();
                other = t[tid ^ j];
            } else {
                other = __shfl_xor(v, j);
            }
            float mn = fminf(v, other), mx = fmaxf(v, other);
            v = (lower == up) ? mn : mx;
        }
    }
    __syncthreads();
    t[tid] = v;
    {
        float c = clipnorm(v, glo, inv2, degen);
        csort[tid] = c;
        ssort[tid] = sqrtf(fmaxf(0.0f, 1.0f - c * c));
        w[tid]     = acosf(c);
    }
    __syncthreads();

    // ---- GAF min/max: extremes of cos(wi+wj) at sums nearest 0, pi, 2pi ----
    {
        float wi = w[tid];
        int jstar = -1;
        if (wi + w[0] >= PI_F) {
            int a = 0, bh = L_ - 1;
            while (a < bh) { int m = (a + bh + 1) >> 1; if (wi + w[m] >= PI_F) a = m; else bh = m - 1; }
            jstar = a;
        }
        float ci = csort[tid], si = ssort[tid];
        float mn = FLT_MAX, mx = -FLT_MAX;
        int cands[4] = {0, L_ - 1, jstar, jstar + 1};
#pragma unroll
        for (int q = 0; q < 4; q++) {
            int j = cands[q];
            if (j >= 0 && j < L_) {
                float g = ci * csort[j] - si * ssort[j];
                mn = fminf(mn, g); mx = fmaxf(mx, g);
            }
        }
#pragma unroll
        for (int off = 32; off; off >>= 1) {
            mn = fminf(mn, __shfl_down(mn, off));
            mx = fmaxf(mx, __shfl_down(mx, off));
        }
        if (lane == 0) { atomicMin(&umin_b, fkey(mn)); atomicMax(&umax_b, fkey(mx)); }
        __syncthreads();
        if (tid == 0) {
            ws[2 + blk * 3 + 0] = unfkey(umin_b);
            ws[2 + blk * 3 + 1] = unfkey(umax_b);
        }
    }

    // ---- RP quantile: order stats 104858 & 104859 (1-indexed) of |ti-tj| over L^2 pairs.
    // False-position (Illinois-safeguarded) value bracketing + exact <=63-candidate finish.
    const float ti = v;
    int pass = 0;
    auto block_count = [&](unsigned c) -> unsigned {
#pragma unroll
        for (int off = 32; off; off >>= 1) c += __shfl_down(c, off);
        if (lane == 0) atomicAdd(&cbuf[pass & 1], c);
        __syncthreads();
        unsigned tot = cbuf[pass & 1];
        if (tid == 0) cbuf[(pass + 1) & 1] = 0u;
        __syncthreads();
        pass++;
        return tot;
    };

    // windows at v=0 (fused dual search; the two chains pipeline)
    int jloLo, jhiLo;
    {
        int aL = 0, bL = tid, aH = tid, bH = L_ - 1;
        while ((aL < bL) | (aH < bH)) {
            int mL = (aL + bL) >> 1;
            int mH = (aH + bH + 1) >> 1;
            float tL = t[aL < bL ? mL : 0];
            float tH = t[aH < bH ? mH : 0];
            if (aL < bL) { if (ti - tL <= 0.0f) bL = mL; else aL = mL + 1; }
            if (aH < bH) { if (tH - ti <= 0.0f) aH = mH; else bH = mH - 1; }
        }
        jloLo = aL; jhiLo = aH;
    }

    const unsigned k1 = 104858u, k2 = 104859u;  // ranks around 0.1*(L^2-1)=104857.5
    unsigned c0 = block_count((unsigned)(jhiLo - jloLo + 1));

    float thr;
    if (c0 >= k1) {
        // v1 = 0
        if (c0 >= k2) thr = 0.0f;
        else {
            float s = FLT_MAX;
            if (jloLo > 0)      s = fminf(s, ti - t[jloLo - 1]);
            if (jhiLo < L_ - 1) s = fminf(s, t[jhiLo + 1] - ti);
#pragma unroll
            for (int off = 32; off; off >>= 1) s = fminf(s, __shfl_down(s, off));
            if (lane == 0) atomicMin(&succ_bits, __float_as_uint(s));
            __syncthreads();
            thr = 0.5f * __uint_as_float(succ_bits);
        }
    } else {
        unsigned cntLo = c0, cntHi = (unsigned)(L_ * L_);
        unsigned bLo = 0u, bHi = __float_as_uint(t[L_ - 1] - t[0]);
        int jloHi = 0, jhiHi = L_ - 1;
        int lastSide = 0, sameCnt = 0, iter = 0;

        while ((bHi - bLo > 1u) && (cntHi - cntLo > 63u) && (iter < 64)) {
            unsigned mb;
            bool forceMid = (sameCnt >= 2) || (iter >= 24);
            if (forceMid) {
                mb = bLo + ((bHi - bLo) >> 1);
            } else {
                float fLo = __uint_as_float(bLo), fHi = __uint_as_float(bHi);
                float f = (float)(k1 - cntLo) / (float)(cntHi - cntLo);
                float vg = fLo + f * (fHi - fLo);
                mb = __float_as_uint(vg);
                if (mb <= bLo) mb = bLo + 1u;
                if (mb >= bHi) mb = bHi - 1u;
            }
            float vm = __uint_as_float(mb);
            // fused dual windowed search at vm
            int aL = jloHi, bL = jloLo, aH = jhiLo, bH = jhiHi;
            while ((aL < bL) | (aH < bH)) {
                int mL = (aL + bL) >> 1;
                int mH = (aH + bH + 1) >> 1;
                float tL = t[aL < bL ? mL : 0];
                float tH = t[aH < bH ? mH : 0];
                if (aL < bL) { if (ti - tL <= vm) bL = mL; else aL = mL + 1; }
                if (aH < bH) { if (tH - ti <= vm) aH = mH; else bH = mH - 1; }
            }
            unsigned tot = block_count((unsigned)(aH - aL + 1));
            int side;
            if (tot >= k1) { bHi = mb; cntHi = tot; jloHi = aL; jhiHi = aH; side = 1; }
            else           { bLo = mb; cntLo = tot; jloLo = aL; jhiLo = aH; side = -1; }
            if (forceMid) { sameCnt = 1; lastSide = side; }
            else if (side == lastSide) sameCnt++;
            else { sameCnt = 1; lastSide = side; }
            iter++;
        }

        if (cntHi - cntLo <= 63u) {
            // exact finish: gather bracket distances (vlo, vhi], wave-0 sort-64, pick ranks
            for (int j = jloHi; j < jloLo; j++) { unsigned p = atomicAdd(&cand_n, 1u); cand[p] = ti - t[j]; }
            for (int j = jhiLo + 1; j <= jhiHi; j++) { unsigned p = atomicAdd(&cand_n, 1u); cand[p] = t[j] - ti; }
            __syncthreads();
            if (tid < 64) {
                unsigned n = cand_n;
                float val = ((unsigned)tid < n) ? cand[tid] : FLT_MAX;
#pragma unroll
                for (int k = 2; k <= 64; k <<= 1) {
                    bool up = ((tid & k) == 0);
#pragma unroll
                    for (int j = k >> 1; j > 0; j >>= 1) {
                        float o = __shfl_xor(val, j);
                        bool lower = ((tid & j) == 0);
                        float mn = fminf(val, o), mx = fmaxf(val, o);
                        val = (lower == up) ? mn : mx;
                    }
                }
                unsigned r1 = k1 - cntLo, r2 = k2 - cntLo;   // 1-indexed within candidates
                float v1l = __shfl(val, (int)r1 - 1);
                float v2l = (r2 <= n) ? __shfl(val, (int)r2 - 1) : FLT_MAX;
                if (tid == 0) { bc_v1v2[0] = v1l; bc_v1v2[1] = v2l; }
            }
            __syncthreads();
            float v1 = bc_v1v2[0], v2m = bc_v1v2[1];
            if (v2m < FLT_MAX) {
                thr = v1 + (v2m - v1) * 0.5f;
            } else {
                // k2 > cntHi: successor = smallest distance > vhi (== smallest > v1)
                float s = FLT_MAX;
                if (jloHi > 0)      s = fminf(s, ti - t[jloHi - 1]);
                if (jhiHi < L_ - 1) s = fminf(s, t[jhiHi + 1] - ti);
#pragma unroll
                for (int off = 32; off; off >>= 1) s = fminf(s, __shfl_down(s, off));
                if (lane == 0) atomicMin(&succ_bits, __float_as_uint(s));
                __syncthreads();
                float v2 = __uint_as_float(succ_bits);
                thr = v1 + (v2 - v1) * 0.5f;
            }
        } else {
            // bits-adjacent exit: only one representable value in (vlo,vhi] -> v1 = vhi
            float v1 = __uint_as_float(bHi);
            if (cntHi >= k2) {
                thr = v1;
            } else {
                float s = FLT_MAX;
                if (jloHi > 0)      s = fminf(s, ti - t[jloHi - 1]);
                if (jhiHi < L_ - 1) s = fminf(s, t[jhiHi + 1] - ti);
#pragma unroll
                for (int off = 32; off; off >>= 1) s = fminf(s, __shfl_down(s, off));
                if (lane == 0) atomicMin(&succ_bits, __float_as_uint(s));
                __syncthreads();
                float v2 = __uint_as_float(succ_bits);
                thr = v1 + (v2 - v1) * 0.5f;
            }
        }
    }
    if (tid == 0) ws[2 + blk * 3 + 2] = thr;
}

// One thread per 4 consecutive pixels; per-plane axis tables staged in LDS (float4 reads).
__global__ __launch_bounds__(256) void k_out(const float* __restrict__ ws,
                                             float4* __restrict__ out4) {
    __shared__ __align__(16) float lds[448];
    __shared__ float sc[3];

    const int tid = threadIdx.x;
    int plane = blockIdx.x / 49;            // block covers 1024 pixels; plane = 49 blocks exactly
    int c = plane & 15, b = plane >> 4, d = c & 7;

    const float* tb = ws + TBL + (b * 8 + d) * TSTR + ((c < 8) ? 0 : 448);
    for (int i = tid; i < 448; i += 256) lds[i] = tb[i];
    if (tid == 0) {
        if (c < 8) {
            float mn = ws[2 + (b * 8 + d) * 3 + 0];
            float mx = ws[2 + (b * 8 + d) * 3 + 1];
            float g = mx - mn;
            sc[0] = mn;
            sc[1] = (g < 1e-8f) ? 0.0f : 1.0f / (g + 1e-8f);
            sc[2] = (g < 1e-8f) ? 1.0f : 0.0f;
        } else {
            sc[0] = ws[2 + (b * 8 + d) * 3 + 2];
        }
    }
    __syncthreads();

    int tix = blockIdx.x * 256 + tid;
    int pix0 = tix << 2;
    int ox0 = pix0 % OUT_;                  // multiple of 4 -> 16B-aligned LDS float4
    int oy  = (pix0 / OUT_) % OUT_;

    float4 r;
    if (c < 8) {
        float mn = sc[0], ginv = sc[1];
        bool gdeg = sc[2] != 0.0f;
        float Cr = lds[oy], Sr = lds[OUT_ + oy];
        float4 Cc = *(const float4*)&lds[ox0];
        float4 Sc = *(const float4*)&lds[OUT_ + ox0];
        r.x = gdeg ? 0.0f : ((Cr * Cc.x - Sr * Sc.x) - mn) * ginv;
        r.y = gdeg ? 0.0f : ((Cr * Cc.y - Sr * Sc.y) - mn) * ginv;
        r.z = gdeg ? 0.0f : ((Cr * Cc.z - Sr * Sc.z) - mn) * ginv;
        r.w = gdeg ? 0.0f : ((Cr * Cc.w - Sr * Sc.w) - mn) * ginv;
    } else {
        float thr = sc[0];
        const float scale = (float)L_ / (float)OUT_;
        float fy = (oy + 0.5f) * scale - 0.5f;
        int y0 = (int)fy; float wy = fy - (float)y0;
        float r0 = lds[oy], r1 = lds[OUT_ + oy];
        float4 q0 = *(const float4*)&lds[ox0];
        float4 q1 = *(const float4*)&lds[OUT_ + ox0];
        float qq0[4] = {q0.x, q0.y, q0.z, q0.w};
        float qq1[4] = {q1.x, q1.y, q1.z, q1.w};
        float res[4];
#pragma unroll
        for (int p = 0; p < 4; p++) {
            float fx = (ox0 + p + 0.5f) * scale - 0.5f;
            int x0i = (int)fx; float wx = fx - (float)x0i;
            float v00 = (fabsf(r0 - qq0[p]) <= thr) ? 1.0f : 0.0f;
            float v01 = (fabsf(r0 - qq1[p]) <= thr) ? 1.0f : 0.0f;
            float v10 = (fabsf(r1 - qq0[p]) <= thr) ? 1.0f : 0.0f;
            float v11 = (fabsf(r1 - qq1[p]) <= thr) ? 1.0f : 0.0f;
            float top = v00 + wx * (v01 - v00);
            float bot = v10 + wx * (v11 - v10);
            res[p] = top + wy * (bot - top);
        }
        r = make_float4(res[0], res[1], res[2], res[3]);
    }
    out4[tix] = r;
}

extern "C" void kernel_launch(void* const* d_in, const int* in_sizes, int n_in,
                              void* d_out, int out_size, void* d_ws, size_t ws_size,
                              hipStream_t stream) {
    const float* x = (const float*)d_in[0];
    float* ws = (float*)d_ws;

    k_stats<<<B_ * D_, 1024, 0, stream>>>(x, ws);
    k_out<<<NT4 / 256, 256, 0, stream>>>(ws, (float4*)d_out);
}

// Round 5
// 96.755 us; speedup vs baseline: 1.8853x; 1.3835x over previous
//
#include <hip/hip_runtime.h>
#include <cfloat>
#include <math.h>

#define B_ 4
#define L_ 1024
#define D_ 8
#define OUT_ 224
#define NPIX (B_ * 2 * D_ * OUT_ * OUT_)   // 3211264
#define NT4  (NPIX / 4)                    // 802816 = 3136 * 256 exactly
#define PI_F 3.14159265358979323846f
#define TBL 128                            // float offset of per-(b,d) tables in ws
#define TSTR 896                           // per-(b,d): CL[224] SL[224] RV0[224] RV1[224]

__device__ __forceinline__ float clipnorm(float v, float lo, float inv2, int degen) {
    float xn = degen ? -1.0f : ((v - lo) * inv2 - 1.0f);
    return fminf(fmaxf(xn, -1.0f + 1e-6f), 1.0f - 1e-6f);
}
__device__ __forceinline__ unsigned fkey(float f) {
    unsigned u = __float_as_uint(f);
    return (u & 0x80000000u) ? ~u : (u | 0x80000000u);
}
__device__ __forceinline__ float unfkey(unsigned k) {
    unsigned u = (k & 0x80000000u) ? (k ^ 0x80000000u) : ~k;
    return __uint_as_float(u);
}

// One block per (b,d). 1024 threads.
__global__ __launch_bounds__(1024) void k_stats(const float* __restrict__ x,
                                                float* __restrict__ ws) {
    __shared__ float t[L_];
    __shared__ float csort[L_], ssort[L_], w[L_];
    __shared__ unsigned part[2][16];
    __shared__ unsigned umin_a, umax_a, umin_b, umax_b, succ_bits;
    __shared__ unsigned cand_n;
    __shared__ float cand[64];
    __shared__ float bc_v1v2[2];

    const int tid  = threadIdx.x;
    const int lane = tid & 63;
    const int wave = tid >> 6;
    const int blk  = blockIdx.x;
    const int b = blk >> 3, d = blk & 7;

    if (tid == 0) {
        umin_a = 0xFFFFFFFFu; umax_a = 0u;
        umin_b = 0xFFFFFFFFu; umax_b = 0u;
        succ_bits = 0xFFFFFFFFu;
        cand_n = 0u;
    }
    __syncthreads();

    // ---- global min/max over all of x (x = 128KB, L2-hot) ----
    {
        const float4* x4 = (const float4*)x;
        float lo = FLT_MAX, hi = -FLT_MAX;
        for (int i = tid; i < (B_ * L_ * D_) / 4; i += 1024) {
            float4 q = x4[i];
            lo = fminf(fminf(fminf(lo, q.x), q.y), fminf(q.z, q.w));
            hi = fmaxf(fmaxf(fmaxf(hi, q.x), q.y), fmaxf(q.z, q.w));
        }
#pragma unroll
        for (int off = 32; off; off >>= 1) {
            lo = fminf(lo, __shfl_down(lo, off));
            hi = fmaxf(hi, __shfl_down(hi, off));
        }
        if (lane == 0) { atomicMin(&umin_a, fkey(lo)); atomicMax(&umax_a, fkey(hi)); }
    }
    __syncthreads();
    const float glo = unfkey(umin_a), ghi = unfkey(umax_a);
    if (blk == 0 && tid == 0) { ws[0] = glo; ws[1] = ghi; }
    const float rng  = ghi - glo;
    const int degen  = rng < 1e-8f;
    const float inv2 = 2.0f / (rng + 1e-8f);

    // ---- per-(b,d) axis tables for k_out (separable bilinear) ----
    if (tid < 2 * OUT_) {
        const float scale = (float)L_ / (float)OUT_;
        int o = (tid < OUT_) ? tid : tid - OUT_;
        float fx = (o + 0.5f) * scale - 0.5f;
        int x0 = (int)fx; float wx = fx - (float)x0;
        float q0 = x[(b * L_ + x0) * D_ + d];
        float q1 = x[(b * L_ + x0 + 1) * D_ + d];
        float* base = ws + TBL + blk * TSTR;
        if (tid < OUT_) {
            float c0 = clipnorm(q0, glo, inv2, degen), c1 = clipnorm(q1, glo, inv2, degen);
            float s0 = sqrtf(fmaxf(0.0f, 1.0f - c0 * c0)), s1 = sqrtf(fmaxf(0.0f, 1.0f - c1 * c1));
            base[o]        = c0 + wx * (c1 - c0);   // CL
            base[OUT_ + o] = s0 + wx * (s1 - s0);   // SL
        } else {
            base[448 + o] = q0;                     // RV0
            base[672 + o] = q1;                     // RV1
        }
    }

    // ---- bitonic sort of this (b,d) series; register + shfl, LDS only j>=64 ----
    float v = x[(b * L_ + tid) * D_ + d];
    for (int k = 2; k <= L_; k <<= 1) {
        bool up = ((tid & k) == 0);
        for (int j = k >> 1; j > 0; j >>= 1) {
            bool lower = ((tid & j) == 0);
            float other;
            if (j >= 64) {
                __syncthreads();
                t[tid] = v;
                __syncthreads();
                other = t[tid ^ j];
            } else {
                other = __shfl_xor(v, j);
            }
            float mn = fminf(v, other), mx = fmaxf(v, other);
            v = (lower == up) ? mn : mx;
        }
    }
    __syncthreads();
    t[tid] = v;
    {
        float c = clipnorm(v, glo, inv2, degen);
        csort[tid] = c;
        ssort[tid] = sqrtf(fmaxf(0.0f, 1.0f - c * c));
        w[tid]     = acosf(c);
    }
    __syncthreads();

    // ---- GAF min/max: extremes of cos(wi+wj) at sums nearest 0, pi, 2pi ----
    {
        float wi = w[tid];
        int jstar = -1;
        if (wi + w[0] >= PI_F) {
            int a = 0, bh = L_ - 1;
            while (a < bh) { int m = (a + bh + 1) >> 1; if (wi + w[m] >= PI_F) a = m; else bh = m - 1; }
            jstar = a;
        }
        float ci = csort[tid], si = ssort[tid];
        float mn = FLT_MAX, mx = -FLT_MAX;
        int cands[4] = {0, L_ - 1, jstar, jstar + 1};
#pragma unroll
        for (int q = 0; q < 4; q++) {
            int j = cands[q];
            if (j >= 0 && j < L_) {
                float g = ci * csort[j] - si * ssort[j];
                mn = fminf(mn, g); mx = fmaxf(mx, g);
            }
        }
#pragma unroll
        for (int off = 32; off; off >>= 1) {
            mn = fminf(mn, __shfl_down(mn, off));
            mx = fmaxf(mx, __shfl_down(mx, off));
        }
        if (lane == 0) { atomicMin(&umin_b, fkey(mn)); atomicMax(&umax_b, fkey(mx)); }
        __syncthreads();
        if (tid == 0) {
            ws[2 + blk * 3 + 0] = unfkey(umin_b);
            ws[2 + blk * 3 + 1] = unfkey(umax_b);
        }
    }

    // ---- RP quantile: order stats 104858 & 104859 (1-indexed) of |ti-tj| over L^2 pairs.
    // Proper Illinois regula-falsi on the value axis + exact <=63-candidate finish.
    const float ti = v;
    int pass = 0;
    // block reduce: wave partials, double-buffered, ONE barrier, broadcast reads
    auto block_count = [&](unsigned c) -> unsigned {
#pragma unroll
        for (int off = 32; off; off >>= 1) c += __shfl_down(c, off);
        int pb = pass & 1;
        if (lane == 0) part[pb][wave] = c;
        __syncthreads();
        unsigned tot = 0;
#pragma unroll
        for (int w2 = 0; w2 < 16; w2++) tot += part[pb][w2];
        pass++;
        return tot;
    };

    // windows at v=0 (fused dual search)
    int jloA_, jhiA_;
    {
        int aL = 0, bL = tid, aH = tid, bH = L_ - 1;
        while ((aL < bL) | (aH < bH)) {
            int mL = (aL + bL) >> 1;
            int mH = (aH + bH + 1) >> 1;
            float tL = t[aL < bL ? mL : 0];
            float tH = t[aH < bH ? mH : 0];
            if (aL < bL) { if (ti - tL <= 0.0f) bL = mL; else aL = mL + 1; }
            if (aH < bH) { if (tH - ti <= 0.0f) aH = mH; else bH = mH - 1; }
        }
        jloA_ = aL; jhiA_ = aH;
    }

    const unsigned k1 = 104858u, k2 = 104859u;  // ranks around 0.1*(L^2-1)=104857.5
    unsigned c0 = block_count((unsigned)(jhiA_ - jloA_ + 1));

    float thr;
    if (c0 >= k1) {
        if (c0 >= k2) thr = 0.0f;
        else {
            float s = FLT_MAX;
            if (jloA_ > 0)      s = fminf(s, ti - t[jloA_ - 1]);
            if (jhiA_ < L_ - 1) s = fminf(s, t[jhiA_ + 1] - ti);
#pragma unroll
            for (int off = 32; off; off >>= 1) s = fminf(s, __shfl_down(s, off));
            if (lane == 0) atomicMin(&succ_bits, __float_as_uint(s));
            __syncthreads();
            thr = 0.5f * __uint_as_float(succ_bits);
        }
    } else {
        unsigned aBits = 0u, bBits = __float_as_uint(t[L_ - 1] - t[0]);
        unsigned cntLo = c0, cntHi = (unsigned)(L_ * L_);
        int jloB_ = 0, jhiB_ = L_ - 1;          // windows at the b (upper) endpoint
        // Illinois state: signed residuals g = cnt - k1 at each endpoint (scaled copies)
        float sga = (float)((long long)c0 - (long long)k1);        // < 0
        float sgb = (float)((long long)(L_ * L_) - (long long)k1); // > 0
        int lastSide = 0, sameCnt = 0;

        while ((bBits - aBits > 1u) && (cntHi - cntLo > 63u)) {
            unsigned mb;
            if (sameCnt >= 3) {
                mb = aBits + ((bBits - aBits) >> 1);   // stagnation insurance (bit midpoint)
                sameCnt = 0;
            } else {
                float va = __uint_as_float(aBits), vb = __uint_as_float(bBits);
                float vg = va - sga * (vb - va) / (sgb - sga);
                mb = __float_as_uint(vg);
                if (mb <= aBits) mb = aBits + 1u;
                else if (mb >= bBits) mb = bBits - 1u;
            }
            float vm = __uint_as_float(mb);
            // fused dual windowed search at vm
            int aL = jloB_, bL = jloA_, aH = jhiA_, bH = jhiB_;
            while ((aL < bL) | (aH < bH)) {
                int mL = (aL + bL) >> 1;
                int mH = (aH + bH + 1) >> 1;
                float tL = t[aL < bL ? mL : 0];
                float tH = t[aH < bH ? mH : 0];
                if (aL < bL) { if (ti - tL <= vm) bL = mL; else aL = mL + 1; }
                if (aH < bH) { if (tH - ti <= vm) aH = mH; else bH = mH - 1; }
            }
            unsigned tot = block_count((unsigned)(aH - aL + 1));
            long long g = (long long)tot - (long long)k1;
            if (g >= 0) {
                bBits = mb; cntHi = tot; jloB_ = aL; jhiB_ = aH;
                sgb = fmaxf((float)g, 0.5f);
                if (lastSide == 1) { sga *= 0.5f; sameCnt++; } else sameCnt = 1;
                lastSide = 1;
            } else {
                aBits = mb; cntLo = tot; jloA_ = aL; jhiA_ = aH;
                sga = fminf((float)g, -0.5f);
                if (lastSide == -1) { sgb *= 0.5f; sameCnt++; } else sameCnt = 1;
                lastSide = -1;
            }
        }

        if (cntHi - cntLo <= 63u) {
            // exact finish: gather bracket distances in (va, vb], wave-0 sort-64, pick ranks
            for (int j = jloB_; j < jloA_; j++) { unsigned p = atomicAdd(&cand_n, 1u); cand[p] = ti - t[j]; }
            for (int j = jhiA_ + 1; j <= jhiB_; j++) { unsigned p = atomicAdd(&cand_n, 1u); cand[p] = t[j] - ti; }
            __syncthreads();
            if (tid < 64) {
                unsigned n = cand_n;
                float val = ((unsigned)tid < n) ? cand[tid] : FLT_MAX;
#pragma unroll
                for (int k = 2; k <= 64; k <<= 1) {
                    bool up = ((tid & k) == 0);
#pragma unroll
                    for (int j = k >> 1; j > 0; j >>= 1) {
                        float o = __shfl_xor(val, j);
                        bool lower = ((tid & j) == 0);
                        float mn = fminf(val, o), mx = fmaxf(val, o);
                        val = (lower == up) ? mn : mx;
                    }
                }
                unsigned r1 = k1 - cntLo, r2 = k2 - cntLo;   // 1-indexed within candidates
                float v1l = __shfl(val, (int)r1 - 1);
                float v2l = (r2 <= n) ? __shfl(val, (int)r2 - 1) : FLT_MAX;
                if (tid == 0) { bc_v1v2[0] = v1l; bc_v1v2[1] = v2l; }
            }
            __syncthreads();
            float v1 = bc_v1v2[0], v2m = bc_v1v2[1];
            if (v2m < FLT_MAX) {
                thr = v1 + (v2m - v1) * 0.5f;
            } else {
                // k2-th is the successor beyond vb
                float s = FLT_MAX;
                if (jloB_ > 0)      s = fminf(s, ti - t[jloB_ - 1]);
                if (jhiB_ < L_ - 1) s = fminf(s, t[jhiB_ + 1] - ti);
#pragma unroll
                for (int off = 32; off; off >>= 1) s = fminf(s, __shfl_down(s, off));
                if (lane == 0) atomicMin(&succ_bits, __float_as_uint(s));
                __syncthreads();
                float v2 = __uint_as_float(succ_bits);
                thr = v1 + (v2 - v1) * 0.5f;
            }
        } else {
            // bits-adjacent: count(a)<k1<=count(b), no representable value between -> v1=u2f(b)
            float v1 = __uint_as_float(bBits);
            if (cntHi >= k2) {
                thr = v1;
            } else {
                float s = FLT_MAX;
                if (jloB_ > 0)      s = fminf(s, ti - t[jloB_ - 1]);
                if (jhiB_ < L_ - 1) s = fminf(s, t[jhiB_ + 1] - ti);
#pragma unroll
                for (int off = 32; off; off >>= 1) s = fminf(s, __shfl_down(s, off));
                if (lane == 0) atomicMin(&succ_bits, __float_as_uint(s));
                __syncthreads();
                float v2 = __uint_as_float(succ_bits);
                thr = v1 + (v2 - v1) * 0.5f;
            }
        }
    }
    if (tid == 0) ws[2 + blk * 3 + 2] = thr;
}

// One thread per 4 consecutive pixels; per-plane axis tables staged in LDS (float4 reads).
__global__ __launch_bounds__(256) void k_out(const float* __restrict__ ws,
                                             float4* __restrict__ out4) {
    __shared__ __align__(16) float lds[448];
    __shared__ float sc[3];

    const int tid = threadIdx.x;
    int plane = blockIdx.x / 49;            // block covers 1024 pixels; plane = 49 blocks exactly
    int c = plane & 15, b = plane >> 4, d = c & 7;

    const float* tb = ws + TBL + (b * 8 + d) * TSTR + ((c < 8) ? 0 : 448);
    for (int i = tid; i < 448; i += 256) lds[i] = tb[i];
    if (tid == 0) {
        if (c < 8) {
            float mn = ws[2 + (b * 8 + d) * 3 + 0];
            float mx = ws[2 + (b * 8 + d) * 3 + 1];
            float g = mx - mn;
            sc[0] = mn;
            sc[1] = (g < 1e-8f) ? 0.0f : 1.0f / (g + 1e-8f);
            sc[2] = (g < 1e-8f) ? 1.0f : 0.0f;
        } else {
            sc[0] = ws[2 + (b * 8 + d) * 3 + 2];
        }
    }
    __syncthreads();

    int tix = blockIdx.x * 256 + tid;
    int pix0 = tix << 2;
    int ox0 = pix0 % OUT_;                  // multiple of 4 -> 16B-aligned LDS float4
    int oy  = (pix0 / OUT_) % OUT_;

    float4 r;
    if (c < 8) {
        float mn = sc[0], ginv = sc[1];
        bool gdeg = sc[2] != 0.0f;
        float Cr = lds[oy], Sr = lds[OUT_ + oy];
        float4 Cc = *(const float4*)&lds[ox0];
        float4 Sc = *(const float4*)&lds[OUT_ + ox0];
        r.x = gdeg ? 0.0f : ((Cr * Cc.x - Sr * Sc.x) - mn) * ginv;
        r.y = gdeg ? 0.0f : ((Cr * Cc.y - Sr * Sc.y) - mn) * ginv;
        r.z = gdeg ? 0.0f : ((Cr * Cc.z - Sr * Sc.z) - mn) * ginv;
        r.w = gdeg ? 0.0f : ((Cr * Cc.w - Sr * Sc.w) - mn) * ginv;
    } else {
        float thr = sc[0];
        const float scale = (float)L_ / (float)OUT_;
        float fy = (oy + 0.5f) * scale - 0.5f;
        int y0 = (int)fy; float wy = fy - (float)y0;
        float r0 = lds[oy], r1 = lds[OUT_ + oy];
        float4 q0 = *(const float4*)&lds[ox0];
        float4 q1 = *(const float4*)&lds[OUT_ + ox0];
        float qq0[4] = {q0.x, q0.y, q0.z, q0.w};
        float qq1[4] = {q1.x, q1.y, q1.z, q1.w};
        float res[4];
#pragma unroll
        for (int p = 0; p < 4; p++) {
            float fx = (ox0 + p + 0.5f) * scale - 0.5f;
            int x0i = (int)fx; float wx = fx - (float)x0i;
            float v00 = (fabsf(r0 - qq0[p]) <= thr) ? 1.0f : 0.0f;
            float v01 = (fabsf(r0 - qq1[p]) <= thr) ? 1.0f : 0.0f;
            float v10 = (fabsf(r1 - qq0[p]) <= thr) ? 1.0f : 0.0f;
            float v11 = (fabsf(r1 - qq1[p]) <= thr) ? 1.0f : 0.0f;
            float top = v00 + wx * (v01 - v00);
            float bot = v10 + wx * (v11 - v10);
            res[p] = top + wy * (bot - top);
        }
        r = make_float4(res[0], res[1], res[2], res[3]);
    }
    out4[tix] = r;
}

extern "C" void kernel_launch(void* const* d_in, const int* in_sizes, int n_in,
                              void* d_out, int out_size, void* d_ws, size_t ws_size,
                              hipStream_t stream) {
    const float* x = (const float*)d_in[0];
    float* ws = (float*)d_ws;

    k_stats<<<B_ * D_, 1024, 0, stream>>>(x, ws);
    k_out<<<NT4 / 256, 256, 0, stream>>>(ws, (float4*)d_out);
}

// Round 9
// 96.664 us; speedup vs baseline: 1.8871x; 1.0009x over previous
//
#include <hip/hip_runtime.h>
#include <cfloat>
#include <math.h>

#define B_ 4
#define L_ 1024
#define D_ 8
#define OUT_ 224
#define NPIX (B_ * 2 * D_ * OUT_ * OUT_)   // 3211264
#define NT4  (NPIX / 4)                    // 802816 = 3136 * 256 exactly
#define PI_F 3.14159265358979323846f
#define TBL 128                            // float offset of per-(b,d) tables in ws
#define TSTR 896                           // per-(b,d): CL[224] SL[224] RV0[224] RV1[224]

__device__ __forceinline__ float clipnorm(float v, float lo, float inv2, int degen) {
    float xn = degen ? -1.0f : ((v - lo) * inv2 - 1.0f);
    return fminf(fmaxf(xn, -1.0f + 1e-6f), 1.0f - 1e-6f);
}
__device__ __forceinline__ unsigned fkey(float f) {
    unsigned u = __float_as_uint(f);
    return (u & 0x80000000u) ? ~u : (u | 0x80000000u);
}
__device__ __forceinline__ float unfkey(unsigned k) {
    unsigned u = (k & 0x80000000u) ? (k ^ 0x80000000u) : ~k;
    return __uint_as_float(u);
}

// One block per (b,d). 1024 threads. (R5 — last green configuration.)
__global__ __launch_bounds__(1024) void k_stats(const float* __restrict__ x,
                                                float* __restrict__ ws) {
    __shared__ float t[L_];
    __shared__ float csort[L_], ssort[L_], w[L_];
    __shared__ unsigned part[2][16];
    __shared__ unsigned umin_a, umax_a, umin_b, umax_b, succ_bits;
    __shared__ unsigned cand_n;
    __shared__ float cand[64];
    __shared__ float bc_v1v2[2];

    const int tid  = threadIdx.x;
    const int lane = tid & 63;
    const int wave = tid >> 6;
    const int blk  = blockIdx.x;
    const int b = blk >> 3, d = blk & 7;

    if (tid == 0) {
        umin_a = 0xFFFFFFFFu; umax_a = 0u;
        umin_b = 0xFFFFFFFFu; umax_b = 0u;
        succ_bits = 0xFFFFFFFFu;
        cand_n = 0u;
    }
    __syncthreads();

    // ---- global min/max over all of x (x = 128KB, L2-hot) ----
    {
        const float4* x4 = (const float4*)x;
        float lo = FLT_MAX, hi = -FLT_MAX;
        for (int i = tid; i < (B_ * L_ * D_) / 4; i += 1024) {
            float4 q = x4[i];
            lo = fminf(fminf(fminf(lo, q.x), q.y), fminf(q.z, q.w));
            hi = fmaxf(fmaxf(fmaxf(hi, q.x), q.y), fmaxf(q.z, q.w));
        }
#pragma unroll
        for (int off = 32; off; off >>= 1) {
            lo = fminf(lo, __shfl_down(lo, off));
            hi = fmaxf(hi, __shfl_down(hi, off));
        }
        if (lane == 0) { atomicMin(&umin_a, fkey(lo)); atomicMax(&umax_a, fkey(hi)); }
    }
    __syncthreads();
    const float glo = unfkey(umin_a), ghi = unfkey(umax_a);
    if (blk == 0 && tid == 0) { ws[0] = glo; ws[1] = ghi; }
    const float rng  = ghi - glo;
    const int degen  = rng < 1e-8f;
    const float inv2 = 2.0f / (rng + 1e-8f);

    // ---- per-(b,d) axis tables for k_out (separable bilinear) ----
    if (tid < 2 * OUT_) {
        const float scale = (float)L_ / (float)OUT_;
        int o = (tid < OUT_) ? tid : tid - OUT_;
        float fx = (o + 0.5f) * scale - 0.5f;
        int x0 = (int)fx; float wx = fx - (float)x0;
        float q0 = x[(b * L_ + x0) * D_ + d];
        float q1 = x[(b * L_ + x0 + 1) * D_ + d];
        float* base = ws + TBL + blk * TSTR;
        if (tid < OUT_) {
            float c0 = clipnorm(q0, glo, inv2, degen), c1 = clipnorm(q1, glo, inv2, degen);
            float s0 = sqrtf(fmaxf(0.0f, 1.0f - c0 * c0)), s1 = sqrtf(fmaxf(0.0f, 1.0f - c1 * c1));
            base[o]        = c0 + wx * (c1 - c0);   // CL
            base[OUT_ + o] = s0 + wx * (s1 - s0);   // SL
        } else {
            base[448 + o] = q0;                     // RV0
            base[672 + o] = q1;                     // RV1
        }
    }

    // ---- bitonic sort of this (b,d) series; register + shfl, LDS only j>=64 ----
    float v = x[(b * L_ + tid) * D_ + d];
    for (int k = 2; k <= L_; k <<= 1) {
        bool up = ((tid & k) == 0);
        for (int j = k >> 1; j > 0; j >>= 1) {
            bool lower = ((tid & j) == 0);
            float other;
            if (j >= 64) {
                __syncthreads();
                t[tid] = v;
                __syncthreads();
                other = t[tid ^ j];
            } else {
                other = __shfl_xor(v, j);
            }
            float mn = fminf(v, other), mx = fmaxf(v, other);
            v = (lower == up) ? mn : mx;
        }
    }
    __syncthreads();
    t[tid] = v;
    {
        float c = clipnorm(v, glo, inv2, degen);
        csort[tid] = c;
        ssort[tid] = sqrtf(fmaxf(0.0f, 1.0f - c * c));
        w[tid]     = acosf(c);
    }
    __syncthreads();

    // ---- GAF min/max: extremes of cos(wi+wj) at sums nearest 0, pi, 2pi ----
    {
        float wi = w[tid];
        int jstar = -1;
        if (wi + w[0] >= PI_F) {
            int a = 0, bh = L_ - 1;
            while (a < bh) { int m = (a + bh + 1) >> 1; if (wi + w[m] >= PI_F) a = m; else bh = m - 1; }
            jstar = a;
        }
        float ci = csort[tid], si = ssort[tid];
        float mn = FLT_MAX, mx = -FLT_MAX;
        int cands[4] = {0, L_ - 1, jstar, jstar + 1};
#pragma unroll
        for (int q = 0; q < 4; q++) {
            int j = cands[q];
            if (j >= 0 && j < L_) {
                float g = ci * csort[j] - si * ssort[j];
                mn = fminf(mn, g); mx = fmaxf(mx, g);
            }
        }
#pragma unroll
        for (int off = 32; off; off >>= 1) {
            mn = fminf(mn, __shfl_down(mn, off));
            mx = fmaxf(mx, __shfl_down(mx, off));
        }
        if (lane == 0) { atomicMin(&umin_b, fkey(mn)); atomicMax(&umax_b, fkey(mx)); }
        __syncthreads();
        if (tid == 0) {
            ws[2 + blk * 3 + 0] = unfkey(umin_b);
            ws[2 + blk * 3 + 1] = unfkey(umax_b);
        }
    }

    // ---- RP quantile: order stats 104858 & 104859 (1-indexed) of |ti-tj| over L^2 pairs.
    // Proper Illinois regula-falsi on the value axis + exact <=63-candidate finish.
    const float ti = v;
    int pass = 0;
    // block reduce: wave partials, double-buffered, ONE barrier, broadcast reads
    auto block_count = [&](unsigned c) -> unsigned {
#pragma unroll
        for (int off = 32; off; off >>= 1) c += __shfl_down(c, off);
        int pb = pass & 1;
        if (lane == 0) part[pb][wave] = c;
        __syncthreads();
        unsigned tot = 0;
#pragma unroll
        for (int w2 = 0; w2 < 16; w2++) tot += part[pb][w2];
        pass++;
        return tot;
    };

    // windows at v=0 (fused dual search)
    int jloA_, jhiA_;
    {
        int aL = 0, bL = tid, aH = tid, bH = L_ - 1;
        while ((aL < bL) | (aH < bH)) {
            int mL = (aL + bL) >> 1;
            int mH = (aH + bH + 1) >> 1;
            float tL = t[aL < bL ? mL : 0];
            float tH = t[aH < bH ? mH : 0];
            if (aL < bL) { if (ti - tL <= 0.0f) bL = mL; else aL = mL + 1; }
            if (aH < bH) { if (tH - ti <= 0.0f) aH = mH; else bH = mH - 1; }
        }
        jloA_ = aL; jhiA_ = aH;
    }

    const unsigned k1 = 104858u, k2 = 104859u;  // ranks around 0.1*(L^2-1)=104857.5
    unsigned c0 = block_count((unsigned)(jhiA_ - jloA_ + 1));

    float thr;
    if (c0 >= k1) {
        if (c0 >= k2) thr = 0.0f;
        else {
            float s = FLT_MAX;
            if (jloA_ > 0)      s = fminf(s, ti - t[jloA_ - 1]);
            if (jhiA_ < L_ - 1) s = fminf(s, t[jhiA_ + 1] - ti);
#pragma unroll
            for (int off = 32; off; off >>= 1) s = fminf(s, __shfl_down(s, off));
            if (lane == 0) atomicMin(&succ_bits, __float_as_uint(s));
            __syncthreads();
            thr = 0.5f * __uint_as_float(succ_bits);
        }
    } else {
        unsigned aBits = 0u, bBits = __float_as_uint(t[L_ - 1] - t[0]);
        unsigned cntLo = c0, cntHi = (unsigned)(L_ * L_);
        int jloB_ = 0, jhiB_ = L_ - 1;          // windows at the b (upper) endpoint
        // Illinois state: signed residuals g = cnt - k1 at each endpoint (scaled copies)
        float sga = (float)((long long)c0 - (long long)k1);        // < 0
        float sgb = (float)((long long)(L_ * L_) - (long long)k1); // > 0
        int lastSide = 0, sameCnt = 0;

        while ((bBits - aBits > 1u) && (cntHi - cntLo > 63u)) {
            unsigned mb;
            if (sameCnt >= 3) {
                mb = aBits + ((bBits - aBits) >> 1);   // stagnation insurance (bit midpoint)
                sameCnt = 0;
            } else {
                float va = __uint_as_float(aBits), vb = __uint_as_float(bBits);
                float vg = va - sga * (vb - va) / (sgb - sga);
                mb = __float_as_uint(vg);
                if (mb <= aBits) mb = aBits + 1u;
                else if (mb >= bBits) mb = bBits - 1u;
            }
            float vm = __uint_as_float(mb);
            // fused dual windowed search at vm
            int aL = jloB_, bL = jloA_, aH = jhiA_, bH = jhiB_;
            while ((aL < bL) | (aH < bH)) {
                int mL = (aL + bL) >> 1;
                int mH = (aH + bH + 1) >> 1;
                float tL = t[aL < bL ? mL : 0];
                float tH = t[aH < bH ? mH : 0];
                if (aL < bL) { if (ti - tL <= vm) bL = mL; else aL = mL + 1; }
                if (aH < bH) { if (tH - ti <= vm) aH = mH; else bH = mH - 1; }
            }
            unsigned tot = block_count((unsigned)(aH - aL + 1));
            long long g = (long long)tot - (long long)k1;
            if (g >= 0) {
                bBits = mb; cntHi = tot; jloB_ = aL; jhiB_ = aH;
                sgb = fmaxf((float)g, 0.5f);
                if (lastSide == 1) { sga *= 0.5f; sameCnt++; } else sameCnt = 1;
                lastSide = 1;
            } else {
                aBits = mb; cntLo = tot; jloA_ = aL; jhiA_ = aH;
                sga = fminf((float)g, -0.5f);
                if (lastSide == -1) { sgb *= 0.5f; sameCnt++; } else sameCnt = 1;
                lastSide = -1;
            }
        }

        if (cntHi - cntLo <= 63u) {
            // exact finish: gather bracket distances in (va, vb], wave-0 sort-64, pick ranks
            for (int j = jloB_; j < jloA_; j++) { unsigned p = atomicAdd(&cand_n, 1u); cand[p] = ti - t[j]; }
            for (int j = jhiA_ + 1; j <= jhiB_; j++) { unsigned p = atomicAdd(&cand_n, 1u); cand[p] = t[j] - ti; }
            __syncthreads();
            if (tid < 64) {
                unsigned n = cand_n;
                float val = ((unsigned)tid < n) ? cand[tid] : FLT_MAX;
#pragma unroll
                for (int k = 2; k <= 64; k <<= 1) {
                    bool up = ((tid & k) == 0);
#pragma unroll
                    for (int j = k >> 1; j > 0; j >>= 1) {
                        float o = __shfl_xor(val, j);
                        bool lower = ((tid & j) == 0);
                        float mn = fminf(val, o), mx = fmaxf(val, o);
                        val = (lower == up) ? mn : mx;
                    }
                }
                unsigned r1 = k1 - cntLo, r2 = k2 - cntLo;   // 1-indexed within candidates
                float v1l = __shfl(val, (int)r1 - 1);
                float v2l = (r2 <= n) ? __shfl(val, (int)r2 - 1) : FLT_MAX;
                if (tid == 0) { bc_v1v2[0] = v1l; bc_v1v2[1] = v2l; }
            }
            __syncthreads();
            float v1 = bc_v1v2[0], v2m = bc_v1v2[1];
            if (v2m < FLT_MAX) {
                thr = v1 + (v2m - v1) * 0.5f;
            } else {
                // k2-th is the successor beyond vb
                float s = FLT_MAX;
                if (jloB_ > 0)      s = fminf(s, ti - t[jloB_ - 1]);
                if (jhiB_ < L_ - 1) s = fminf(s, t[jhiB_ + 1] - ti);
#pragma unroll
                for (int off = 32; off; off >>= 1) s = fminf(s, __shfl_down(s, off));
                if (lane == 0) atomicMin(&succ_bits, __float_as_uint(s));
                __syncthreads();
                float v2 = __uint_as_float(succ_bits);
                thr = v1 + (v2 - v1) * 0.5f;
            }
        } else {
            // bits-adjacent: count(a)<k1<=count(b), no representable value between -> v1=u2f(b)
            float v1 = __uint_as_float(bBits);
            if (cntHi >= k2) {
                thr = v1;
            } else {
                float s = FLT_MAX;
                if (jloB_ > 0)      s = fminf(s, ti - t[jloB_ - 1]);
                if (jhiB_ < L_ - 1) s = fminf(s, t[jhiB_ + 1] - ti);
#pragma unroll
                for (int off = 32; off; off >>= 1) s = fminf(s, __shfl_down(s, off));
                if (lane == 0) atomicMin(&succ_bits, __float_as_uint(s));
                __syncthreads();
                float v2 = __uint_as_float(succ_bits);
                thr = v1 + (v2 - v1) * 0.5f;
            }
        }
    }
    if (tid == 0) ws[2 + blk * 3 + 2] = thr;
}

// One thread per 4 consecutive pixels; per-plane axis tables staged in LDS (float4 reads).
__global__ __launch_bounds__(256) void k_out(const float* __restrict__ ws,
                                             float4* __restrict__ out4) {
    __shared__ __align__(16) float lds[448];
    __shared__ float sc[3];

    const int tid = threadIdx.x;
    int plane = blockIdx.x / 49;            // block covers 1024 pixels; plane = 49 blocks exactly
    int c = plane & 15, b = plane >> 4, d = c & 7;

    const float* tb = ws + TBL + (b * 8 + d) * TSTR + ((c < 8) ? 0 : 448);
    for (int i = tid; i < 448; i += 256) lds[i] = tb[i];
    if (tid == 0) {
        if (c < 8) {
            float mn = ws[2 + (b * 8 + d) * 3 + 0];
            float mx = ws[2 + (b * 8 + d) * 3 + 1];
            float g = mx - mn;
            sc[0] = mn;
            sc[1] = (g < 1e-8f) ? 0.0f : 1.0f / (g + 1e-8f);
            sc[2] = (g < 1e-8f) ? 1.0f : 0.0f;
        } else {
            sc[0] = ws[2 + (b * 8 + d) * 3 + 2];
        }
    }
    __syncthreads();

    int tix = blockIdx.x * 256 + tid;
    int pix0 = tix << 2;
    int ox0 = pix0 % OUT_;                  // multiple of 4 -> 16B-aligned LDS float4
    int oy  = (pix0 / OUT_) % OUT_;

    float4 r;
    if (c < 8) {
        float mn = sc[0], ginv = sc[1];
        bool gdeg = sc[2] != 0.0f;
        float Cr = lds[oy], Sr = lds[OUT_ + oy];
        float4 Cc = *(const float4*)&lds[ox0];
        float4 Sc = *(const float4*)&lds[OUT_ + ox0];
        r.x = gdeg ? 0.0f : ((Cr * Cc.x - Sr * Sc.x) - mn) * ginv;
        r.y = gdeg ? 0.0f : ((Cr * Cc.y - Sr * Sc.y) - mn) * ginv;
        r.z = gdeg ? 0.0f : ((Cr * Cc.z - Sr * Sc.z) - mn) * ginv;
        r.w = gdeg ? 0.0f : ((Cr * Cc.w - Sr * Sc.w) - mn) * ginv;
    } else {
        float thr = sc[0];
        const float scale = (float)L_ / (float)OUT_;
        float fy = (oy + 0.5f) * scale - 0.5f;
        int y0 = (int)fy; float wy = fy - (float)y0;
        float r0 = lds[oy], r1 = lds[OUT_ + oy];
        float4 q0 = *(const float4*)&lds[ox0];
        float4 q1 = *(const float4*)&lds[OUT_ + ox0];
        float qq0[4] = {q0.x, q0.y, q0.z, q0.w};
        float qq1[4] = {q1.x, q1.y, q1.z, q1.w};
        float res[4];
#pragma unroll
        for (int p = 0; p < 4; p++) {
            float fx = (ox0 + p + 0.5f) * scale - 0.5f;
            int x0i = (int)fx; float wx = fx - (float)x0i;
            float v00 = (fabsf(r0 - qq0[p]) <= thr) ? 1.0f : 0.0f;
            float v01 = (fabsf(r0 - qq1[p]) <= thr) ? 1.0f : 0.0f;
            float v10 = (fabsf(r1 - qq0[p]) <= thr) ? 1.0f : 0.0f;
            float v11 = (fabsf(r1 - qq1[p]) <= thr) ? 1.0f : 0.0f;
            float top = v00 + wx * (v01 - v00);
            float bot = v10 + wx * (v11 - v10);
            res[p] = top + wy * (bot - top);
        }
        r = make_float4(res[0], res[1], res[2], res[3]);
    }
    out4[tix] = r;
}

extern "C" void kernel_launch(void* const* d_in, const int* in_sizes, int n_in,
                              void* d_out, int out_size, void* d_ws, size_t ws_size,
                              hipStream_t stream) {
    const float* x = (const float*)d_in[0];
    float* ws = (float*)d_ws;

    k_stats<<<B_ * D_, 1024, 0, stream>>>(x, ws);
    k_out<<<NT4 / 256, 256, 0, stream>>>(ws, (float4*)d_out);
}